// Round 8
// baseline (899.344 us; speedup 1.0000x reference)
//
#include <hip/hip_runtime.h>
#include <hip/hip_bf16.h>

// ---------------------------------------------------------------------------
// 2-layer GCN, N=100000 nodes, E=3200000 edges, 128 -> 64 -> 64.
// out[i] = dinv[i] * ( sum_{e: dst=i} g[src_e] + g[i] ) + b,  g = (x@W)*dinv,
// dinv = rsqrt(indeg+1).
//
// CSR build (round-6, kept): zero global atomics, ~1x write amplification.
//
// Round-8 change: feature-sliced aggregation. Round-7 profile: agg bound by
// L2-miss service (~2TB/s) because each XCD's random gathers address all of
// G (12.8MB) vs 4MB per-XCD L2. Now G is stored as 8 slices Gs[j][node][8]
// (bf16, 1.6MB/slice); block with blockIdx&7==j aggregates slice j, and the
// de-facto round-robin blockIdx->XCD mapping pins slice j to XCD j -> the
// gather footprint per XCD is L2-resident. Cost: esrc is streamed 8x
// (sequential, nontemporal). Wave = 8 edges x 8 features, f32 accumulate,
// 3x shfl_xor row reduce. hbuf/out stay standard layout -> GEMM input paths
// unchanged (only the GEMM epilogue store is sliced).
// ---------------------------------------------------------------------------

#define CHUNK 4096      // edges per localsort block
#define CB    512       // nodes per coarse bucket (=> <=256 buckets, u8 keys)
#define NCMAX 1024      // max chunks supported by k_fine LDS

__device__ __forceinline__ unsigned short f2bf(float f) {
    union { float f; unsigned int u; } x; x.f = f;
    unsigned int r = (x.u + 0x7FFF + ((x.u >> 16) & 1)) >> 16;  // RNE
    return (unsigned short)r;
}
__device__ __forceinline__ float bf2f(unsigned short u) {
    union { unsigned int u; float f; } x; x.u = ((unsigned int)u) << 16;
    return x.f;
}

__global__ void k_initf(int* flag) { *flag = 0; }

// Decide whether edge_index is stored as int32 or int64 words.
__global__ void k_detect(const int* ei, int* flag, long long E) {
    int t = blockIdx.x * blockDim.x + threadIdx.x;   // 1024 threads
    long long k = (long long)t * (E / 1024);
    if (k < E) {
        if (ei[2 * k + 1] != 0) atomicOr(flag, 1);   // 1 => int32 layout
    }
}

__device__ __forceinline__ int edge_at(const int* ei, int is32, long long idx) {
    return is32 ? ei[idx] : ei[2 * idx];
}

// ---------------------------------------------------------------------------
// Pass 1: per-chunk LDS counting sort by coarse bucket (d >> 9).
// ---------------------------------------------------------------------------
__global__ __launch_bounds__(256) void k_localsort(const int* __restrict__ ei,
                                                   const int* __restrict__ flag,
                                                   int* __restrict__ sorted_all,
                                                   int* __restrict__ off_local,
                                                   long long E, int NC) {
    __shared__ unsigned int  val[CHUNK];
    __shared__ unsigned char key[CHUNK];
    __shared__ unsigned int  srt[CHUNK];
    __shared__ int cnt[256], pos[256], cur[256];
    const int b = blockIdx.x;
    const int t = threadIdx.x;
    const long long base = (long long)b * CHUNK;
    const int nE = (int)((E - base < CHUNK) ? (E - base) : CHUNK);
    const int is32 = *flag;

    for (int i = t; i < nE; i += 256) {
        int s = edge_at(ei, is32, base + i);
        int d = edge_at(ei, is32, E + base + i);
        val[i] = (unsigned)s | ((unsigned)(d & (CB - 1)) << 17);
        key[i] = (unsigned char)(d >> 9);
    }
    cnt[t] = 0;
    __syncthreads();
    for (int i = t; i < nE; i += 256) atomicAdd(&cnt[key[i]], 1);
    __syncthreads();
    pos[t] = cnt[t];
    __syncthreads();
    for (int d = 1; d < 256; d <<= 1) {
        int x = (t >= d) ? pos[t - d] : 0;
        __syncthreads();
        pos[t] += x;
        __syncthreads();
    }
    cur[t] = pos[t] - cnt[t];                       // exclusive offset
    if (t < NC) off_local[b * (NC + 1) + t] = pos[t] - cnt[t];
    if (t == 0) off_local[b * (NC + 1) + NC] = nE;
    __syncthreads();
    for (int i = t; i < nE; i += 256) {
        int k = key[i];
        int p = atomicAdd(&cur[k], 1);
        srt[p] = val[i];
    }
    __syncthreads();
    for (int i = t; i < nE; i += 256) sorted_all[base + i] = (int)srt[i];
}

// Per-coarse-bucket totals: column sums of the off-diff matrix.
__global__ __launch_bounds__(256) void k_colsum(const int* __restrict__ off_local,
                                                int* __restrict__ totals,
                                                int nchunk, int NC) {
    __shared__ int s[256];
    const int c = blockIdx.x;
    const int t = threadIdx.x;
    int sum = 0;
    for (int b = t; b < nchunk; b += 256) {
        int rb = b * (NC + 1);
        sum += off_local[rb + c + 1] - off_local[rb + c];
    }
    s[t] = sum;
    __syncthreads();
    for (int d = 128; d > 0; d >>= 1) {
        if (t < d) s[t] += s[t + d];
        __syncthreads();
    }
    if (t == 0) totals[c] = s[0];
}

// Exclusive scan of totals (NC <= 256) -> cbase; also rowp[n] = E.
__global__ __launch_bounds__(256) void k_cscan(const int* __restrict__ totals,
                                               int* __restrict__ cbase,
                                               int* __restrict__ rowp,
                                               int NC, int n) {
    __shared__ int s[256];
    const int t = threadIdx.x;
    int v = (t < NC) ? totals[t] : 0;
    s[t] = v;
    __syncthreads();
    for (int d = 1; d < 256; d <<= 1) {
        int x = (t >= d) ? s[t - d] : 0;
        __syncthreads();
        s[t] += x;
        __syncthreads();
    }
    if (t < NC) cbase[t] = s[t] - v;
    if (t == NC - 1) { cbase[NC] = s[t]; rowp[n] = s[t]; }
}

// ---------------------------------------------------------------------------
// Pass 2: one block per coarse bucket -> exact CSR + rowp + dinv.
// ---------------------------------------------------------------------------
__global__ __launch_bounds__(512) void k_fine(const int* __restrict__ sorted_all,
                                              const int* __restrict__ off_local,
                                              const int* __restrict__ cbase,
                                              int* __restrict__ esrc,
                                              int* __restrict__ rowp,
                                              float* __restrict__ dinv,
                                              int nchunk, int NC, int n) {
    __shared__ int segoff[NCMAX];
    __shared__ int segend[NCMAX];
    __shared__ int hist[CB], incl[CB], cur[CB];
    const int c = blockIdx.x;
    const int t = threadIdx.x;
    for (int b = t; b < nchunk; b += 512) {
        int rb = b * (NC + 1);
        segoff[b] = b * CHUNK + off_local[rb + c];
        segend[b] = b * CHUNK + off_local[rb + c + 1];
    }
    hist[t] = 0;
    __syncthreads();
    for (int b = t; b < nchunk; b += 512)
        for (int i = segoff[b]; i < segend[b]; ++i)
            atomicAdd(&hist[((unsigned)sorted_all[i] >> 17) & (CB - 1)], 1);
    __syncthreads();
    incl[t] = hist[t];
    __syncthreads();
    for (int d = 1; d < 512; d <<= 1) {
        int x = (t >= d) ? incl[t - d] : 0;
        __syncthreads();
        incl[t] += x;
        __syncthreads();
    }
    const int base = cbase[c];
    cur[t] = base + incl[t] - hist[t];
    const int node = c * CB + t;
    if (node < n) {
        rowp[node] = base + incl[t] - hist[t];
        dinv[node] = rsqrtf((float)(hist[t] + 1));   // +1 self loop
    }
    __syncthreads();
    for (int b = t; b < nchunk; b += 512)
        for (int i = segoff[b]; i < segend[b]; ++i) {
            unsigned v = (unsigned)sorted_all[i];
            int dl = (v >> 17) & (CB - 1);
            int p = atomicAdd(&cur[dl], 1);
            esrc[p] = (int)(v & 0x1FFFF);
        }
}

// ---------------------------------------------------------------------------
// Register-tiled GEMM: Gs[8][n][8](bf16) = ((X * W) * dinv), feature-sliced.
// Block = 256 threads, tile = 64x64, thread = 4x4 micro-tile, BK=32.
// Thread covers cols tx*4..tx*4+3 -> slice jj = tx>>1, offset (tx&1)*4.
// ---------------------------------------------------------------------------
template <int K_IN>
__global__ __launch_bounds__(256) void k_gemm2(const float* __restrict__ X,
                                               const float* __restrict__ W,
                                               const float* __restrict__ dinv,
                                               unsigned short* __restrict__ G,
                                               int n) {
    __shared__ float Xs[64][33];
    __shared__ float Ws[32][64];
    const int t = threadIdx.x;
    const int tx = t & 15;
    const int ty = t >> 4;
    const int r0 = blockIdx.x * 64;

    float acc[4][4] = {};

    for (int kb = 0; kb < K_IN; kb += 32) {
        {
            const int kq = t & 7;
            const int rr = t >> 3;
#pragma unroll
            for (int it = 0; it < 2; ++it) {
                int r = r0 + rr + it * 32;
                int rc = r < n ? r : n - 1;
                float4 xv = *(const float4*)(X + (size_t)rc * K_IN + kb + kq * 4);
                float* xd = &Xs[rr + it * 32][kq * 4];
                xd[0] = xv.x; xd[1] = xv.y; xd[2] = xv.z; xd[3] = xv.w;
            }
        }
        {
            const int cq = t & 15;
            const int kr = t >> 4;
#pragma unroll
            for (int it = 0; it < 2; ++it) {
                float4 wv = *(const float4*)(W + (size_t)(kb + kr + it * 16) * 64 + cq * 4);
                *(float4*)&Ws[kr + it * 16][cq * 4] = wv;
            }
        }
        __syncthreads();
#pragma unroll 8
        for (int k = 0; k < 32; ++k) {
            float4 wv = *(const float4*)&Ws[k][tx * 4];
            float x0 = Xs[ty * 4 + 0][k];
            float x1 = Xs[ty * 4 + 1][k];
            float x2 = Xs[ty * 4 + 2][k];
            float x3 = Xs[ty * 4 + 3][k];
            acc[0][0] = fmaf(x0, wv.x, acc[0][0]);
            acc[0][1] = fmaf(x0, wv.y, acc[0][1]);
            acc[0][2] = fmaf(x0, wv.z, acc[0][2]);
            acc[0][3] = fmaf(x0, wv.w, acc[0][3]);
            acc[1][0] = fmaf(x1, wv.x, acc[1][0]);
            acc[1][1] = fmaf(x1, wv.y, acc[1][1]);
            acc[1][2] = fmaf(x1, wv.z, acc[1][2]);
            acc[1][3] = fmaf(x1, wv.w, acc[1][3]);
            acc[2][0] = fmaf(x2, wv.x, acc[2][0]);
            acc[2][1] = fmaf(x2, wv.y, acc[2][1]);
            acc[2][2] = fmaf(x2, wv.z, acc[2][2]);
            acc[2][3] = fmaf(x2, wv.w, acc[2][3]);
            acc[3][0] = fmaf(x3, wv.x, acc[3][0]);
            acc[3][1] = fmaf(x3, wv.y, acc[3][1]);
            acc[3][2] = fmaf(x3, wv.z, acc[3][2]);
            acc[3][3] = fmaf(x3, wv.w, acc[3][3]);
        }
        __syncthreads();
    }
    const int jj = tx >> 1;              // feature slice
    const int fo = (tx & 1) * 4;         // offset within slice
#pragma unroll
    for (int j = 0; j < 4; ++j) {
        int r = r0 + ty * 4 + j;
        if (r < n) {
            float dv = dinv[r];
            union { unsigned short u[4]; uint2 v; } o;
            o.u[0] = f2bf(acc[j][0] * dv);
            o.u[1] = f2bf(acc[j][1] * dv);
            o.u[2] = f2bf(acc[j][2] * dv);
            o.u[3] = f2bf(acc[j][3] * dv);
            *(uint2*)(G + ((size_t)jj * n + r) * 8 + fo) = o.v;
        }
    }
}

// ---------------------------------------------------------------------------
// Feature-sliced aggregation. blockIdx&7 = slice j (de-facto XCD j): gathers
// hit a 1.6MB L2-resident slice. Wave = 8 edges x 8 features; f32 accumulate;
// row reduce via 3x shfl_xor; lanes 0-7 write the 8 output features.
// esrc is streamed nontemporally (8x re-read, sequential) to protect the
// slice in L2. OUT is standard [node][64] f32 layout.
// ---------------------------------------------------------------------------
template <bool RELU>
__global__ __launch_bounds__(256) void k_agg_s(const unsigned short* __restrict__ G,
                                               const int* __restrict__ rowp,
                                               const int* __restrict__ esrc,
                                               const float* __restrict__ dinv,
                                               const float* __restrict__ bias,
                                               float* __restrict__ OUT, int n) {
    const int j = blockIdx.x & 7;                 // feature slice
    const int part = blockIdx.x >> 3;
    const int lane = threadIdx.x & 63;
    const int w = threadIdx.x >> 6;               // wave 0..3
    const int o = lane & 7;                       // feature within slice
    const int g8 = lane >> 3;                     // edge subgroup 0..7
    const unsigned short* __restrict__ Gj = G + (size_t)j * n * 8;
    const float bj = bias[j * 8 + o];

    const int ibase = part * 64 + w * 16;
    for (int rr = 0; rr < 16; ++rr) {
        const int i = ibase + rr;
        if (i >= n) break;
        const int e0 = rowp[i], e1 = rowp[i + 1];
        float acc = 0.f;
        int eg = e0 + g8;
        for (; eg + 24 < e1; eg += 32) {          // 4 groups of 8 edges
            int s0 = __builtin_nontemporal_load(&esrc[eg]);
            int s1 = __builtin_nontemporal_load(&esrc[eg + 8]);
            int s2 = __builtin_nontemporal_load(&esrc[eg + 16]);
            int s3 = __builtin_nontemporal_load(&esrc[eg + 24]);
            unsigned short a0 = Gj[(size_t)s0 * 8 + o];
            unsigned short a1 = Gj[(size_t)s1 * 8 + o];
            unsigned short a2 = Gj[(size_t)s2 * 8 + o];
            unsigned short a3 = Gj[(size_t)s3 * 8 + o];
            acc += bf2f(a0) + bf2f(a1) + bf2f(a2) + bf2f(a3);
        }
        for (; eg < e1; eg += 8) {
            int s = __builtin_nontemporal_load(&esrc[eg]);
            acc += bf2f(Gj[(size_t)s * 8 + o]);
        }
        acc += __shfl_xor(acc, 8, 64);
        acc += __shfl_xor(acc, 16, 64);
        acc += __shfl_xor(acc, 32, 64);
        float gs = bf2f(Gj[(size_t)i * 8 + o]);   // self loop
        float res = dinv[i] * (acc + gs) + bj;
        if (RELU) res = fmaxf(res, 0.f);
        if (lane < 8) OUT[(size_t)i * 64 + j * 8 + o] = res;
    }
}

extern "C" void kernel_launch(void* const* d_in, const int* in_sizes, int n_in,
                              void* d_out, int out_size, void* d_ws, size_t ws_size,
                              hipStream_t stream) {
    const float* x = (const float*)d_in[0];
    const int* ei = (const int*)d_in[1];
    const float* W1 = (const float*)d_in[2];
    const float* b1 = (const float*)d_in[3];
    const float* W2 = (const float*)d_in[4];
    const float* b2 = (const float*)d_in[5];
    float* out = (float*)d_out;

    const int N = in_sizes[0] / 128;          // requires N <= 131072 (17-bit src)
    const long long E = in_sizes[1] / 2;
    const int NCHUNK = (int)((E + CHUNK - 1) / CHUNK);  // <= NCMAX
    const int NC = (N + CB - 1) / CB;                    // coarse buckets <= 256

    char* p = (char*)d_ws;
    size_t off = 0;
    auto take = [&](size_t bytes) -> void* {
        void* r = p + off;
        off += (bytes + 255) & ~(size_t)255;
        return r;
    };
    int* flag = (int*)take(4);
    int* off_local = (int*)take((size_t)NCHUNK * (NC + 1) * 4);
    int* totals = (int*)take((size_t)NC * 4);
    int* cbase = (int*)take((size_t)(NC + 1) * 4);
    int* rowp = (int*)take((size_t)(N + 1) * 4);
    float* dinv = (float*)take((size_t)N * 4);
    int* sorted_all = (int*)take((size_t)NCHUNK * CHUNK * 4);
    int* esrc = (int*)take((size_t)E * 4);
    unsigned short* gbuf = (unsigned short*)take((size_t)N * 64 * 2);
    float* hbuf = (float*)take((size_t)N * 64 * 4);
    (void)ws_size; (void)n_in; (void)out_size;

    k_initf<<<1, 1, 0, stream>>>(flag);
    k_detect<<<4, 256, 0, stream>>>(ei, flag, E);
    k_localsort<<<NCHUNK, 256, 0, stream>>>(ei, flag, sorted_all, off_local, E, NC);
    k_colsum<<<NC, 256, 0, stream>>>(off_local, totals, NCHUNK, NC);
    k_cscan<<<1, 256, 0, stream>>>(totals, cbase, rowp, NC, N);
    k_fine<<<NC, 512, 0, stream>>>(sorted_all, off_local, cbase, esrc, rowp, dinv,
                                   NCHUNK, NC, N);

    const int NPART = (N + 63) / 64;
    k_gemm2<128><<<(N + 63) / 64, 256, 0, stream>>>(x, W1, dinv, gbuf, N);
    k_agg_s<true><<<8 * NPART, 256, 0, stream>>>(gbuf, rowp, esrc, dinv, b1, hbuf, N);
    k_gemm2<64><<<(N + 63) / 64, 256, 0, stream>>>(hbuf, W2, dinv, gbuf, N);
    k_agg_s<false><<<8 * NPART, 256, 0, stream>>>(gbuf, rowp, esrc, dinv, b2, out, N);
}

// Round 9
// 342.708 us; speedup vs baseline: 2.6242x; 2.6242x over previous
//
#include <hip/hip_runtime.h>
#include <hip/hip_bf16.h>

// ---------------------------------------------------------------------------
// 2-layer GCN, N=100000 nodes, E=3200000 edges, 128 -> 64 -> 64.
// out[i] = dinv[i] * ( sum_{e: dst=i} g[src_e] + g[i] ) + b,  g = (x@W)*dinv,
// dinv = rsqrt(indeg+1).
//
// CSR build (round-6): zero global atomics, ~1x write amplification.
// Aggregation (round-7): wave-per-node, contiguous 128B bf16 gathers, f32
// accumulate. Round-8 lesson: do NOT feature-slice the gather — 8x more
// random transactions at 16B each is transaction-rate bound (66G trans/s)
// and 4x slower despite lower FETCH. Keep gathers 128B-contiguous.
//
// Round-9 changes:
//  - layer-1 agg fused with the 64x64 layer-2 linear (k_agg_f): h stays in
//    registers (f32), W2 matvec via __shfl + LDS-staged W2, writes g2 bf16.
//    Removes hbuf (51MB traffic) + the gemm64 kernel.
//  - k_fine reads chunk segments wave-cooperatively (coalesced).
// ---------------------------------------------------------------------------

#define CHUNK 4096      // edges per localsort block
#define CB    512       // nodes per coarse bucket (=> <=256 buckets, u8 keys)
#define NCMAX 1024      // max chunks supported by k_fine LDS

__device__ __forceinline__ unsigned short f2bf(float f) {
    union { float f; unsigned int u; } x; x.f = f;
    unsigned int r = (x.u + 0x7FFF + ((x.u >> 16) & 1)) >> 16;  // RNE
    return (unsigned short)r;
}
__device__ __forceinline__ float bf2f(unsigned short u) {
    union { unsigned int u; float f; } x; x.u = ((unsigned int)u) << 16;
    return x.f;
}

__global__ void k_initf(int* flag) { *flag = 0; }

// Decide whether edge_index is stored as int32 or int64 words.
__global__ void k_detect(const int* ei, int* flag, long long E) {
    int t = blockIdx.x * blockDim.x + threadIdx.x;   // 1024 threads
    long long k = (long long)t * (E / 1024);
    if (k < E) {
        if (ei[2 * k + 1] != 0) atomicOr(flag, 1);   // 1 => int32 layout
    }
}

__device__ __forceinline__ int edge_at(const int* ei, int is32, long long idx) {
    return is32 ? ei[idx] : ei[2 * idx];
}

// ---------------------------------------------------------------------------
// Pass 1: per-chunk LDS counting sort by coarse bucket (d >> 9).
// ---------------------------------------------------------------------------
__global__ __launch_bounds__(256) void k_localsort(const int* __restrict__ ei,
                                                   const int* __restrict__ flag,
                                                   int* __restrict__ sorted_all,
                                                   int* __restrict__ off_local,
                                                   long long E, int NC) {
    __shared__ unsigned int  val[CHUNK];
    __shared__ unsigned char key[CHUNK];
    __shared__ unsigned int  srt[CHUNK];
    __shared__ int cnt[256], pos[256], cur[256];
    const int b = blockIdx.x;
    const int t = threadIdx.x;
    const long long base = (long long)b * CHUNK;
    const int nE = (int)((E - base < CHUNK) ? (E - base) : CHUNK);
    const int is32 = *flag;

    for (int i = t; i < nE; i += 256) {
        int s = edge_at(ei, is32, base + i);
        int d = edge_at(ei, is32, E + base + i);
        val[i] = (unsigned)s | ((unsigned)(d & (CB - 1)) << 17);
        key[i] = (unsigned char)(d >> 9);
    }
    cnt[t] = 0;
    __syncthreads();
    for (int i = t; i < nE; i += 256) atomicAdd(&cnt[key[i]], 1);
    __syncthreads();
    pos[t] = cnt[t];
    __syncthreads();
    for (int d = 1; d < 256; d <<= 1) {
        int x = (t >= d) ? pos[t - d] : 0;
        __syncthreads();
        pos[t] += x;
        __syncthreads();
    }
    cur[t] = pos[t] - cnt[t];                       // exclusive offset
    if (t < NC) off_local[b * (NC + 1) + t] = pos[t] - cnt[t];
    if (t == 0) off_local[b * (NC + 1) + NC] = nE;
    __syncthreads();
    for (int i = t; i < nE; i += 256) {
        int k = key[i];
        int p = atomicAdd(&cur[k], 1);
        srt[p] = val[i];
    }
    __syncthreads();
    for (int i = t; i < nE; i += 256) sorted_all[base + i] = (int)srt[i];
}

// Per-coarse-bucket totals: column sums of the off-diff matrix.
__global__ __launch_bounds__(256) void k_colsum(const int* __restrict__ off_local,
                                                int* __restrict__ totals,
                                                int nchunk, int NC) {
    __shared__ int s[256];
    const int c = blockIdx.x;
    const int t = threadIdx.x;
    int sum = 0;
    for (int b = t; b < nchunk; b += 256) {
        int rb = b * (NC + 1);
        sum += off_local[rb + c + 1] - off_local[rb + c];
    }
    s[t] = sum;
    __syncthreads();
    for (int d = 128; d > 0; d >>= 1) {
        if (t < d) s[t] += s[t + d];
        __syncthreads();
    }
    if (t == 0) totals[c] = s[0];
}

// Exclusive scan of totals (NC <= 256) -> cbase; also rowp[n] = E.
__global__ __launch_bounds__(256) void k_cscan(const int* __restrict__ totals,
                                               int* __restrict__ cbase,
                                               int* __restrict__ rowp,
                                               int NC, int n) {
    __shared__ int s[256];
    const int t = threadIdx.x;
    int v = (t < NC) ? totals[t] : 0;
    s[t] = v;
    __syncthreads();
    for (int d = 1; d < 256; d <<= 1) {
        int x = (t >= d) ? s[t - d] : 0;
        __syncthreads();
        s[t] += x;
        __syncthreads();
    }
    if (t < NC) cbase[t] = s[t] - v;
    if (t == NC - 1) { cbase[NC] = s[t]; rowp[n] = s[t]; }
}

// ---------------------------------------------------------------------------
// Pass 2: one block per coarse bucket -> exact CSR + rowp + dinv.
// Wave-cooperative segment reads (round-9): lanes sweep a segment together.
// ---------------------------------------------------------------------------
__global__ __launch_bounds__(512) void k_fine(const int* __restrict__ sorted_all,
                                              const int* __restrict__ off_local,
                                              const int* __restrict__ cbase,
                                              int* __restrict__ esrc,
                                              int* __restrict__ rowp,
                                              float* __restrict__ dinv,
                                              int nchunk, int NC, int n) {
    __shared__ int segoff[NCMAX];
    __shared__ int segend[NCMAX];
    __shared__ int hist[CB], incl[CB], cur[CB];
    const int c = blockIdx.x;
    const int t = threadIdx.x;
    const int w = t >> 6;            // wave 0..7
    const int lane = t & 63;
    for (int b = t; b < nchunk; b += 512) {
        int rb = b * (NC + 1);
        segoff[b] = b * CHUNK + off_local[rb + c];
        segend[b] = b * CHUNK + off_local[rb + c + 1];
    }
    hist[t] = 0;
    __syncthreads();
    for (int b = w; b < nchunk; b += 8) {
        const int s0 = segoff[b], s1 = segend[b];
        for (int i = s0 + lane; i < s1; i += 64)
            atomicAdd(&hist[((unsigned)sorted_all[i] >> 17) & (CB - 1)], 1);
    }
    __syncthreads();
    incl[t] = hist[t];
    __syncthreads();
    for (int d = 1; d < 512; d <<= 1) {
        int x = (t >= d) ? incl[t - d] : 0;
        __syncthreads();
        incl[t] += x;
        __syncthreads();
    }
    const int base = cbase[c];
    cur[t] = base + incl[t] - hist[t];
    const int node = c * CB + t;
    if (node < n) {
        rowp[node] = base + incl[t] - hist[t];
        dinv[node] = rsqrtf((float)(hist[t] + 1));   // +1 self loop
    }
    __syncthreads();
    for (int b = w; b < nchunk; b += 8) {
        const int s0 = segoff[b], s1 = segend[b];
        for (int i = s0 + lane; i < s1; i += 64) {
            unsigned v = (unsigned)sorted_all[i];
            int dl = (v >> 17) & (CB - 1);
            int p = atomicAdd(&cur[dl], 1);
            esrc[p] = (int)(v & 0x1FFFF);
        }
    }
}

// ---------------------------------------------------------------------------
// Register-tiled GEMM: G[n x 64](bf16) = (X[n x 128] * W) * dinv.
// Block = 256 threads, tile = 64x64, thread = 4x4 micro-tile, BK=32.
// ---------------------------------------------------------------------------
template <int K_IN>
__global__ __launch_bounds__(256) void k_gemm2(const float* __restrict__ X,
                                               const float* __restrict__ W,
                                               const float* __restrict__ dinv,
                                               unsigned short* __restrict__ G,
                                               int n) {
    __shared__ float Xs[64][33];
    __shared__ float Ws[32][64];
    const int t = threadIdx.x;
    const int tx = t & 15;
    const int ty = t >> 4;
    const int r0 = blockIdx.x * 64;

    float acc[4][4] = {};

    for (int kb = 0; kb < K_IN; kb += 32) {
        {
            const int kq = t & 7;
            const int rr = t >> 3;
#pragma unroll
            for (int it = 0; it < 2; ++it) {
                int r = r0 + rr + it * 32;
                int rc = r < n ? r : n - 1;
                float4 xv = *(const float4*)(X + (size_t)rc * K_IN + kb + kq * 4);
                float* xd = &Xs[rr + it * 32][kq * 4];
                xd[0] = xv.x; xd[1] = xv.y; xd[2] = xv.z; xd[3] = xv.w;
            }
        }
        {
            const int cq = t & 15;
            const int kr = t >> 4;
#pragma unroll
            for (int it = 0; it < 2; ++it) {
                float4 wv = *(const float4*)(W + (size_t)(kb + kr + it * 16) * 64 + cq * 4);
                *(float4*)&Ws[kr + it * 16][cq * 4] = wv;
            }
        }
        __syncthreads();
#pragma unroll 8
        for (int k = 0; k < 32; ++k) {
            float4 wv = *(const float4*)&Ws[k][tx * 4];
            float x0 = Xs[ty * 4 + 0][k];
            float x1 = Xs[ty * 4 + 1][k];
            float x2 = Xs[ty * 4 + 2][k];
            float x3 = Xs[ty * 4 + 3][k];
            acc[0][0] = fmaf(x0, wv.x, acc[0][0]);
            acc[0][1] = fmaf(x0, wv.y, acc[0][1]);
            acc[0][2] = fmaf(x0, wv.z, acc[0][2]);
            acc[0][3] = fmaf(x0, wv.w, acc[0][3]);
            acc[1][0] = fmaf(x1, wv.x, acc[1][0]);
            acc[1][1] = fmaf(x1, wv.y, acc[1][1]);
            acc[1][2] = fmaf(x1, wv.z, acc[1][2]);
            acc[1][3] = fmaf(x1, wv.w, acc[1][3]);
            acc[2][0] = fmaf(x2, wv.x, acc[2][0]);
            acc[2][1] = fmaf(x2, wv.y, acc[2][1]);
            acc[2][2] = fmaf(x2, wv.z, acc[2][2]);
            acc[2][3] = fmaf(x2, wv.w, acc[2][3]);
            acc[3][0] = fmaf(x3, wv.x, acc[3][0]);
            acc[3][1] = fmaf(x3, wv.y, acc[3][1]);
            acc[3][2] = fmaf(x3, wv.z, acc[3][2]);
            acc[3][3] = fmaf(x3, wv.w, acc[3][3]);
        }
        __syncthreads();
    }
#pragma unroll
    for (int j = 0; j < 4; ++j) {
        int r = r0 + ty * 4 + j;
        if (r < n) {
            float dv = dinv[r];
            union { unsigned short u[4]; uint2 v; } o;
            o.u[0] = f2bf(acc[j][0] * dv);
            o.u[1] = f2bf(acc[j][1] * dv);
            o.u[2] = f2bf(acc[j][2] * dv);
            o.u[3] = f2bf(acc[j][3] * dv);
            *(uint2*)(G + (size_t)r * 64 + tx * 4) = o.v;
        }
    }
}

// ---------------------------------------------------------------------------
// Fused layer-1 aggregation + ReLU + 64x64 linear (W2) + dinv scale -> G2 bf16.
// Wave per node (grid-stride): contiguous 128B bf16 gathers, f32 accumulate,
// h stays in registers; matvec h@W2 via __shfl broadcast + LDS-staged W2.
// ---------------------------------------------------------------------------
__global__ __launch_bounds__(256) void k_agg_f(const unsigned short* __restrict__ G,
                                               const int* __restrict__ rowp,
                                               const int* __restrict__ esrc,
                                               const float* __restrict__ dinv,
                                               const float* __restrict__ b1,
                                               const float* __restrict__ W2,
                                               unsigned short* __restrict__ G2,
                                               int n) {
    __shared__ float W2s[64 * 64];
    for (int i = threadIdx.x; i < 1024; i += 256)
        ((float4*)W2s)[i] = ((const float4*)W2)[i];
    __syncthreads();

    const int lane = threadIdx.x & 63;
    const int nw = gridDim.x * 4;
    for (int i = blockIdx.x * 4 + (threadIdx.x >> 6); i < n; i += nw) {
        float acc = bf2f(G[(size_t)i * 64 + lane]);    // self loop
        int e = rowp[i], e1 = rowp[i + 1];
        for (; e + 8 <= e1; e += 8) {
            int s0 = esrc[e], s1 = esrc[e + 1], s2 = esrc[e + 2], s3 = esrc[e + 3];
            int s4 = esrc[e + 4], s5 = esrc[e + 5], s6 = esrc[e + 6], s7 = esrc[e + 7];
            unsigned short a0 = G[(size_t)s0 * 64 + lane];
            unsigned short a1 = G[(size_t)s1 * 64 + lane];
            unsigned short a2 = G[(size_t)s2 * 64 + lane];
            unsigned short a3 = G[(size_t)s3 * 64 + lane];
            unsigned short a4 = G[(size_t)s4 * 64 + lane];
            unsigned short a5 = G[(size_t)s5 * 64 + lane];
            unsigned short a6 = G[(size_t)s6 * 64 + lane];
            unsigned short a7 = G[(size_t)s7 * 64 + lane];
            acc += bf2f(a0) + bf2f(a1) + bf2f(a2) + bf2f(a3)
                 + bf2f(a4) + bf2f(a5) + bf2f(a6) + bf2f(a7);
        }
        for (; e < e1; ++e) acc += bf2f(G[(size_t)esrc[e] * 64 + lane]);
        float dv = dinv[i];
        float res = fmaxf(dv * acc + b1[lane], 0.f);   // h[i][lane]
        // h @ W2 (column = lane) via wave broadcast
        float acc2 = 0.f;
#pragma unroll 8
        for (int k = 0; k < 64; ++k)
            acc2 = fmaf(__shfl(res, k, 64), W2s[k * 64 + lane], acc2);
        G2[(size_t)i * 64 + lane] = f2bf(acc2 * dv);
    }
}

// Layer-2 aggregation (round-7 shape): wave per node, bf16 gathers, f32 accum.
__global__ __launch_bounds__(256) void k_agg2(const unsigned short* __restrict__ G,
                                              const int* __restrict__ rowp,
                                              const int* __restrict__ esrc,
                                              const float* __restrict__ dinv,
                                              const float* __restrict__ bias,
                                              float* __restrict__ OUT, int n) {
    int lane = threadIdx.x & 63;
    int i = blockIdx.x * (blockDim.x >> 6) + (threadIdx.x >> 6);
    if (i >= n) return;
    float acc = bf2f(G[(size_t)i * 64 + lane]);        // self loop
    int e = rowp[i], e1 = rowp[i + 1];
    for (; e + 8 <= e1; e += 8) {
        int s0 = esrc[e], s1 = esrc[e + 1], s2 = esrc[e + 2], s3 = esrc[e + 3];
        int s4 = esrc[e + 4], s5 = esrc[e + 5], s6 = esrc[e + 6], s7 = esrc[e + 7];
        unsigned short a0 = G[(size_t)s0 * 64 + lane];
        unsigned short a1 = G[(size_t)s1 * 64 + lane];
        unsigned short a2 = G[(size_t)s2 * 64 + lane];
        unsigned short a3 = G[(size_t)s3 * 64 + lane];
        unsigned short a4 = G[(size_t)s4 * 64 + lane];
        unsigned short a5 = G[(size_t)s5 * 64 + lane];
        unsigned short a6 = G[(size_t)s6 * 64 + lane];
        unsigned short a7 = G[(size_t)s7 * 64 + lane];
        acc += bf2f(a0) + bf2f(a1) + bf2f(a2) + bf2f(a3)
             + bf2f(a4) + bf2f(a5) + bf2f(a6) + bf2f(a7);
    }
    for (; e < e1; ++e) acc += bf2f(G[(size_t)esrc[e] * 64 + lane]);
    OUT[(size_t)i * 64 + lane] = dinv[i] * acc + bias[lane];
}

extern "C" void kernel_launch(void* const* d_in, const int* in_sizes, int n_in,
                              void* d_out, int out_size, void* d_ws, size_t ws_size,
                              hipStream_t stream) {
    const float* x = (const float*)d_in[0];
    const int* ei = (const int*)d_in[1];
    const float* W1 = (const float*)d_in[2];
    const float* b1 = (const float*)d_in[3];
    const float* W2 = (const float*)d_in[4];
    const float* b2 = (const float*)d_in[5];
    float* out = (float*)d_out;

    const int N = in_sizes[0] / 128;          // requires N <= 131072 (17-bit src)
    const long long E = in_sizes[1] / 2;
    const int NCHUNK = (int)((E + CHUNK - 1) / CHUNK);  // <= NCMAX
    const int NC = (N + CB - 1) / CB;                    // coarse buckets <= 256

    char* p = (char*)d_ws;
    size_t off = 0;
    auto take = [&](size_t bytes) -> void* {
        void* r = p + off;
        off += (bytes + 255) & ~(size_t)255;
        return r;
    };
    int* flag = (int*)take(4);
    int* off_local = (int*)take((size_t)NCHUNK * (NC + 1) * 4);
    int* totals = (int*)take((size_t)NC * 4);
    int* cbase = (int*)take((size_t)(NC + 1) * 4);
    int* rowp = (int*)take((size_t)(N + 1) * 4);
    float* dinv = (float*)take((size_t)N * 4);
    int* sorted_all = (int*)take((size_t)NCHUNK * CHUNK * 4);
    int* esrc = (int*)take((size_t)E * 4);
    unsigned short* gbuf1 = (unsigned short*)take((size_t)N * 64 * 2);
    unsigned short* gbuf2 = (unsigned short*)take((size_t)N * 64 * 2);
    (void)ws_size; (void)n_in; (void)out_size;

    k_initf<<<1, 1, 0, stream>>>(flag);
    k_detect<<<4, 256, 0, stream>>>(ei, flag, E);
    k_localsort<<<NCHUNK, 256, 0, stream>>>(ei, flag, sorted_all, off_local, E, NC);
    k_colsum<<<NC, 256, 0, stream>>>(off_local, totals, NCHUNK, NC);
    k_cscan<<<1, 256, 0, stream>>>(totals, cbase, rowp, NC, N);
    k_fine<<<NC, 512, 0, stream>>>(sorted_all, off_local, cbase, esrc, rowp, dinv,
                                   NCHUNK, NC, N);

    k_gemm2<128><<<(N + 63) / 64, 256, 0, stream>>>(x, W1, dinv, gbuf1, N);
    k_agg_f<<<4096, 256, 0, stream>>>(gbuf1, rowp, esrc, dinv, b1, W2, gbuf2, N);
    k_agg2<<<(N + 3) / 4, 256, 0, stream>>>(gbuf2, rowp, esrc, dinv, b2, out, N);
}